// Round 15
// baseline (48.141 us; speedup 1.0000x reference)
//
#include <hip/hip_runtime.h>

// NT-Xent loss, B=4096, D=256, N=8192, T=0.5
// loss = [ sum_r ( log(sum_{c!=r} exp(2*f_r.f_c)) - 2*f_r.f_pos(r) ) ] / N^2
// v15 = v14 (MX-fp4 triangle halving, no memset, exact-coverage reduce) with
// __launch_bounds__(256,4) — v11's proven occupancy contract (4 blocks/CU,
// 64-VGPR budget that v11's identical per-wave state fit). v14's
// waves_per_eu(2,4) allowed 2 blocks/CU -> 544 blocks took 2 rounds.

#define B_ROWS 4096
#define DIM 256
#define NTOT 8192
#define SCALE_IN 1.69864360f   // sqrt(2*log2(e))
#define QS (16.0f * SCALE_IN)  // fp4 pre-scale; HW scales 2^-4 * 2^-4 undo 256x

typedef int i32x4 __attribute__((ext_vector_type(4)));
typedef int i32x8 __attribute__((ext_vector_type(8)));
typedef float f32x16 __attribute__((ext_vector_type(16)));
typedef __attribute__((address_space(1))) const unsigned int gas_uint;
typedef __attribute__((address_space(3))) unsigned int las_uint;

__device__ __forceinline__ float wave_reduce_add(float v) {
#pragma unroll
    for (int m = 1; m < 64; m <<= 1) v += __shfl_xor(v, m, 64);
    return v;
}

__device__ __forceinline__ i32x8 pad8(i32x4 v) {
    return __builtin_shufflevector(v, v, 0, 1, 2, 3, -1, -1, -1, -1);
}

// fp4 e2m1 encode, values {0,.5,1,1.5,2,3,4,6}, round-to-nearest
__device__ __forceinline__ unsigned fp4_enc(float x) {
    const unsigned s = (x < 0.0f) ? 8u : 0u;
    const float v = fabsf(x);
    unsigned c;
    if (v < 1.25f) {
        c = (v < 0.25f) ? 0u : (v < 0.75f) ? 1u : 2u;
    } else if (v < 2.5f) {
        c = (v < 1.75f) ? 3u : 4u;
    } else {
        c = (v < 3.5f) ? 5u : (v < 5.0f) ? 6u : 7u;
    }
    return s | c;
}

// F4 fragment-panel layout (v11-verified): panel = row>>6 (8KB). 16B chunk
// q = ks*128 + ((row>>5)&1)*64 + khalf*32 + (row&31); k = ks*64 + khalf*32.

// K1: 4 waves/block, one row-pair per wave. Normalize (fp32), quantize to
// fp4*QS into frag-panel layout; exact fp32 positive sims.
__global__ __launch_bounds__(256) void k_norm(const float* __restrict__ zi,
                                              const float* __restrict__ zj,
                                              unsigned char* __restrict__ F4,
                                              float* __restrict__ pos_sim) {
    const int wave = threadIdx.x >> 6;
    const int lane = threadIdx.x & 63;
    const int r = blockIdx.x * 4 + wave;
    const float4 vi = reinterpret_cast<const float4*>(zi + (size_t)r * DIM)[lane];
    const float4 vj = reinterpret_cast<const float4*>(zj + (size_t)r * DIM)[lane];
    float si = vi.x * vi.x + vi.y * vi.y + vi.z * vi.z + vi.w * vi.w;
    float sj = vj.x * vj.x + vj.y * vj.y + vj.z * vj.z + vj.w * vj.w;
    si = wave_reduce_add(si);
    sj = wave_reduce_add(sj);
    const float ri = QS / sqrtf(si);
    const float rj = QS / sqrtf(sj);
    const float a0 = vi.x * ri, a1 = vi.y * ri, a2 = vi.z * ri, a3 = vi.w * ri;
    const float b0 = vj.x * rj, b1 = vj.y * rj, b2 = vj.z * rj, b3 = vj.w * rj;
    const float inv2 = 1.0f / (QS * QS);
    float dot = (a0 * b0 + a1 * b1 + a2 * b2 + a3 * b3) * inv2;
    dot = wave_reduce_add(dot);
    const unsigned short pka = (unsigned short)(fp4_enc(a0) | (fp4_enc(a1) << 4) |
                                                (fp4_enc(a2) << 8) | (fp4_enc(a3) << 12));
    const unsigned short pkb = (unsigned short)(fp4_enc(b0) | (fp4_enc(b1) << 4) |
                                                (fp4_enc(b2) << 8) | (fp4_enc(b3) << 12));
    const int ks = lane >> 4;
    const int kh = (lane >> 3) & 1;
    const int byt = (lane & 7) * 2;
    {
        const size_t addr = (size_t)(r >> 6) * 8192
                            + (size_t)(ks * 128 + ((r >> 5) & 1) * 64 + kh * 32 + (r & 31)) * 16
                            + byt;
        *reinterpret_cast<unsigned short*>(F4 + addr) = pka;
    }
    {
        const int r2 = r + B_ROWS;
        const size_t addr = (size_t)(r2 >> 6) * 8192
                            + (size_t)(ks * 128 + ((r2 >> 5) & 1) * 64 + kh * 32 + (r2 & 31)) * 16
                            + byt;
        *reinterpret_cast<unsigned short*>(F4 + addr) = pkb;
    }
    if (lane == 0) {
        const float ps = 2.0f * dot;
        pos_sim[r] = ps;
        pos_sim[r + B_ROWS] = ps;
    }
}

// K2: triangle block. bid<480: full (rt, ch<rt/4), 8 tiles, row+col sums.
// bid>=480: diag rt=bid-480, ch=rt>>2, nt=2*(rt&3)+2 tiles of which the last
// two are the self-masked diagonal square (row-sums only, no col-sums).
__global__ __launch_bounds__(256, 4)
void k_simsum(const unsigned char* __restrict__ F4, float* __restrict__ Spart) {
    __shared__ unsigned char Bsm[2][8192];
    __shared__ float cl[4 * 512];

    const int bid = blockIdx.x;
    int rt, ch, nt, ncol;
    if (bid < 480) {
        int r = 0, base = 0;
        for (;;) { const int cnt = r >> 2; if (bid < base + cnt) break; base += cnt; ++r; }
        rt = r; ch = bid - base; nt = 8; ncol = 8;
    } else {
        rt = bid - 480; ch = rt >> 2; ncol = 2 * (rt & 3); nt = ncol + 2;
    }

    const int tid = threadIdx.x;
    const int wave = tid >> 6;
    const int lane = tid & 63;
    const int c32 = lane & 31;
    const int l5 = lane >> 5;

    const int wrow0 = rt * 128 + wave * 32;
    const int col0 = ch * 512;

    // A fragments (frag-panel, coalesced 16B/lane): 4 ks x i32x4
    i32x4 a[4];
    {
        const unsigned char* apan = F4 + (size_t)(wrow0 >> 6) * 8192
                                    + (size_t)(((wrow0 >> 5) & 1) * 64 + lane) * 16;
#pragma unroll
        for (int ks = 0; ks < 4; ++ks)
            a[ks] = *reinterpret_cast<const i32x4*>(apan + ks * 2048);
    }

    // stage 64-col tile t (panel ch*8+t, contiguous 8KB); 2 chunks/thread
    auto stage = [&](int buf, int t) {
        const unsigned char* src = F4 + (size_t)(ch * 8 + t) * 8192;
#pragma unroll
        for (int i2 = 0; i2 < 2; ++i2) {
            __builtin_amdgcn_global_load_lds((gas_uint*)(src + (i2 * 256 + tid) * 16),
                                             (las_uint*)(&Bsm[buf][(i2 * 256 + wave * 64) * 16]),
                                             16, 0, 0);
        }
    };

    float sums[16];
#pragma unroll
    for (int g = 0; g < 16; ++g) sums[g] = 0.0f;

    stage(0, 0);
    for (int i = tid; i < 2048; i += 256) cl[i] = 0.0f;
    asm volatile("s_waitcnt vmcnt(0)");
    __syncthreads();

    for (int t = 0; t < nt; ++t) {
        const int buf = t & 1;
        if (t + 1 < nt) stage(buf ^ 1, t + 1);

        f32x16 acc0 = {};
        f32x16 acc1 = {};
#pragma unroll
        for (int ks = 0; ks < 4; ++ks) {
            const unsigned char* base = &Bsm[buf][ks * 2048 + lane * 16];
            const i32x4 b0 = *reinterpret_cast<const i32x4*>(base);
            const i32x4 b1 = *reinterpret_cast<const i32x4*>(base + 1024);
            acc0 = __builtin_amdgcn_mfma_scale_f32_32x32x64_f8f6f4(
                pad8(a[ks]), pad8(b0), acc0, 4, 4, 0, 0x7B7B7B7B, 0, 0x7B7B7B7B);
            acc1 = __builtin_amdgcn_mfma_scale_f32_32x32x64_f8f6f4(
                pad8(a[ks]), pad8(b1), acc1, 4, 4, 0, 0x7B7B7B7B, 0, 0x7B7B7B7B);
        }

        // diagonal self-mask fires only where wave rows == tile cols (diag sq)
        const int cb = col0 + t * 64;
        const bool d0 = (wrow0 == cb);
        const bool d1 = (wrow0 == cb + 32);
        float c0 = 0.0f, c1 = 0.0f;
        if (d0 | d1) {
#pragma unroll
            for (int g = 0; g < 16; ++g) {
                const int rowid = (g & 3) + 8 * (g >> 2) + 4 * l5;
                float e0 = exp2f(acc0[g]);
                float e1 = exp2f(acc1[g]);
                if (d0 && rowid == c32) e0 = 0.0f;
                if (d1 && rowid == c32) e1 = 0.0f;
                sums[g] += e0 + e1;
            }
        } else {
#pragma unroll
            for (int g = 0; g < 16; ++g) {
                const float e0 = exp2f(acc0[g]);
                const float e1 = exp2f(acc1[g]);
                sums[g] += e0 + e1;
                c0 += e0;
                c1 += e1;
            }
            if (t < ncol) {   // emit col-sums (transposed-pair contributions)
                const float c0f = c0 + __shfl_xor(c0, 32, 64);
                const float c1f = c1 + __shfl_xor(c1, 32, 64);
                cl[wave * 512 + t * 64 + l5 * 32 + c32] = l5 ? c1f : c0f;
            }
        }

        asm volatile("s_waitcnt vmcnt(0)");
        __syncthreads();
    }

    // row-sums -> slot ch
#pragma unroll
    for (int g = 0; g < 16; ++g) {
        float s = sums[g];
        s += __shfl_xor(s, 1, 64);
        s += __shfl_xor(s, 2, 64);
        s += __shfl_xor(s, 4, 64);
        s += __shfl_xor(s, 8, 64);
        s += __shfl_xor(s, 16, 64);
        if (c32 == 0) {
            const int row = wrow0 + (g & 3) + 8 * (g >> 2) + 4 * l5;
            Spart[(size_t)ch * NTOT + row] = s;
        }
    }

    // col-sums -> slot 16+rt (cross-wave fold; zeros where not emitted)
#pragma unroll
    for (int i = 0; i < 2; ++i) {
        const int col = tid + i * 256;
        const float tot = cl[col] + cl[512 + col] + cl[1024 + col] + cl[1536 + col];
        Spart[(size_t)(16 + rt) * NTOT + col0 + col] = tot;
    }
}

// K3a: 32 blocks x 256 thr, one row each. Sum EXACTLY the written slots:
// row-slots ch=0..r>>9, col-slots rt=4*(r>>9)..63 (bounds block-uniform).
__global__ __launch_bounds__(256) void k_reduce(const float* __restrict__ Spart,
                                                const float* __restrict__ pos_sim,
                                                float* __restrict__ Bpart) {
    __shared__ float red[4];
    const int r = blockIdx.x * 256 + threadIdx.x;
    const int chr = r >> 9;          // uniform across the block
    float s = 0.0f;
    for (int c = 0; c <= chr; ++c) s += Spart[(size_t)c * NTOT + r];
    for (int rt = 4 * chr; rt < 64; ++rt) s += Spart[(size_t)(16 + rt) * NTOT + r];
    float local = logf(s) - pos_sim[r];
    local = wave_reduce_add(local);
    if ((threadIdx.x & 63) == 0) red[threadIdx.x >> 6] = local;
    __syncthreads();
    if (threadIdx.x == 0) Bpart[blockIdx.x] = red[0] + red[1] + red[2] + red[3];
}

// K3b: single wave folds 32 block partials.
__global__ void k_fin(const float* __restrict__ Bpart, float* __restrict__ out) {
    float v = (threadIdx.x < 32) ? Bpart[threadIdx.x] : 0.0f;
    v = wave_reduce_add(v);
    if (threadIdx.x == 0) out[0] = v / ((float)NTOT * (float)NTOT);
}

extern "C" void kernel_launch(void* const* d_in, const int* in_sizes, int n_in,
                              void* d_out, int out_size, void* d_ws, size_t ws_size,
                              hipStream_t stream) {
    (void)in_sizes; (void)n_in; (void)out_size; (void)ws_size;
    const float* zi = (const float*)d_in[0];
    const float* zj = (const float*)d_in[1];
    float* out = (float*)d_out;

    char* ws = (char*)d_ws;
    unsigned char* F4 = (unsigned char*)ws;                     // 1 MiB fp4 feats, frag-panel order
    float* pos_sim = (float*)(ws + 1048576);                    // 32 KiB
    float* Spart = (float*)(ws + 1048576 + 65536);              // 2.5 MiB (80 slots x 8192)
    float* Bpart = (float*)(ws + 1048576 + 65536 + (size_t)80 * NTOT * 4);

    k_norm<<<B_ROWS / 4, 256, 0, stream>>>(zi, zj, F4, pos_sim);
    k_simsum<<<544, 256, 0, stream>>>(F4, Spart);
    k_reduce<<<NTOT / 256, 256, 0, stream>>>(Spart, pos_sim, Bpart);
    k_fin<<<1, 64, 0, stream>>>(Bpart, out);
}

// Round 16
// 36.291 us; speedup vs baseline: 1.3265x; 1.3265x over previous
//
#include <hip/hip_runtime.h>

// NT-Xent loss, B=4096, D=256, N=8192, T=0.5
// loss = [ sum_r ( log(sum_{c!=r} exp(2*f_r.f_c)) - 2*f_r.f_pos(r) ) ] / N^2
// v16 = v11 (best, 36.5us: MX-fp4 e2m1 scale-2^-4 GEMM, frag-panel layout,
// 2-phase dbuf, 4 waves x 32 rows x 512 cols, (256,4)=128-VGPR budget) with
// 128-col tiles (NTILE 8->4): halves the per-tile vmcnt(0)+barrier drains,
// per-wave register shape byte-identical (two 64-col halves per tile).

#define B_ROWS 4096
#define DIM 256
#define NTOT 8192
#define NCHUNK 16        // col chunks of 512
#define CHUNK_COLS 512
#define NTILE 4          // 4 x 128-col tiles
#define BLK_ROWS 128     // 4 waves * 32 rows
#define SCALE_IN 1.69864360f   // sqrt(2*log2(e))
#define QS (16.0f * SCALE_IN)  // fp4 pre-scale; HW scales 2^-4 * 2^-4 undo 256x

typedef int i32x4 __attribute__((ext_vector_type(4)));
typedef int i32x8 __attribute__((ext_vector_type(8)));
typedef float f32x16 __attribute__((ext_vector_type(16)));
typedef __attribute__((address_space(1))) const unsigned int gas_uint;
typedef __attribute__((address_space(3))) unsigned int las_uint;

__device__ __forceinline__ float wave_reduce_add(float v) {
#pragma unroll
    for (int m = 1; m < 64; m <<= 1) v += __shfl_xor(v, m, 64);
    return v;
}

__device__ __forceinline__ i32x8 pad8(i32x4 v) {
    return __builtin_shufflevector(v, v, 0, 1, 2, 3, -1, -1, -1, -1);
}

// fp4 e2m1 encode, values {0,.5,1,1.5,2,3,4,6}, round-to-nearest
__device__ __forceinline__ unsigned fp4_enc(float x) {
    const unsigned s = (x < 0.0f) ? 8u : 0u;
    const float v = fabsf(x);
    unsigned c;
    if (v < 1.25f) {
        c = (v < 0.25f) ? 0u : (v < 0.75f) ? 1u : 2u;
    } else if (v < 2.5f) {
        c = (v < 1.75f) ? 3u : 4u;
    } else {
        c = (v < 3.5f) ? 5u : (v < 5.0f) ? 6u : 7u;
    }
    return s | c;
}

// F4 fragment-panel layout (v11-verified): panel = row>>6 (8KB). 16B chunk
// q = ks*128 + ((row>>5)&1)*64 + khalf*32 + (row&31); k = ks*64 + khalf*32.

// K1: 4 waves/block, one row-pair per wave. Normalize (fp32), quantize to
// fp4*QS into frag-panel layout; exact fp32 positive sims.
__global__ __launch_bounds__(256) void k_norm(const float* __restrict__ zi,
                                              const float* __restrict__ zj,
                                              unsigned char* __restrict__ F4,
                                              float* __restrict__ pos_sim) {
    const int wave = threadIdx.x >> 6;
    const int lane = threadIdx.x & 63;
    const int r = blockIdx.x * 4 + wave;
    const float4 vi = reinterpret_cast<const float4*>(zi + (size_t)r * DIM)[lane];
    const float4 vj = reinterpret_cast<const float4*>(zj + (size_t)r * DIM)[lane];
    float si = vi.x * vi.x + vi.y * vi.y + vi.z * vi.z + vi.w * vi.w;
    float sj = vj.x * vj.x + vj.y * vj.y + vj.z * vj.z + vj.w * vj.w;
    si = wave_reduce_add(si);
    sj = wave_reduce_add(sj);
    const float ri = QS / sqrtf(si);
    const float rj = QS / sqrtf(sj);
    const float a0 = vi.x * ri, a1 = vi.y * ri, a2 = vi.z * ri, a3 = vi.w * ri;
    const float b0 = vj.x * rj, b1 = vj.y * rj, b2 = vj.z * rj, b3 = vj.w * rj;
    const float inv2 = 1.0f / (QS * QS);
    float dot = (a0 * b0 + a1 * b1 + a2 * b2 + a3 * b3) * inv2;
    dot = wave_reduce_add(dot);
    const unsigned short pka = (unsigned short)(fp4_enc(a0) | (fp4_enc(a1) << 4) |
                                                (fp4_enc(a2) << 8) | (fp4_enc(a3) << 12));
    const unsigned short pkb = (unsigned short)(fp4_enc(b0) | (fp4_enc(b1) << 4) |
                                                (fp4_enc(b2) << 8) | (fp4_enc(b3) << 12));
    const int ks = lane >> 4;
    const int kh = (lane >> 3) & 1;
    const int byt = (lane & 7) * 2;
    {
        const size_t addr = (size_t)(r >> 6) * 8192
                            + (size_t)(ks * 128 + ((r >> 5) & 1) * 64 + kh * 32 + (r & 31)) * 16
                            + byt;
        *reinterpret_cast<unsigned short*>(F4 + addr) = pka;
    }
    {
        const int r2 = r + B_ROWS;
        const size_t addr = (size_t)(r2 >> 6) * 8192
                            + (size_t)(ks * 128 + ((r2 >> 5) & 1) * 64 + kh * 32 + (r2 & 31)) * 16
                            + byt;
        *reinterpret_cast<unsigned short*>(F4 + addr) = pkb;
    }
    if (lane == 0) {
        const float ps = 2.0f * dot;
        pos_sim[r] = ps;
        pos_sim[r + B_ROWS] = ps;
    }
}

// K2: MX-fp4 sim GEMM (32x32x64, scales 2^-4) + fused exp2 row-sum.
// 4 waves x 32 rows x 512 cols; 2-phase dbuf of 128-col tiles (2 x 16KB).
__global__ __launch_bounds__(256, 4) void k_simsum(const unsigned char* __restrict__ F4,
                                                   float* __restrict__ Spart) {
    __shared__ unsigned char Bsm[2][16384];
    const int bid0 = blockIdx.x;
    const int bid = (bid0 & 7) * 128 + (bid0 >> 3);   // XCD swizzle (1024 blocks)
    const int ch = bid >> 6;   // 16 chunks of 512 cols
    const int rt = bid & 63;   // 64 row tiles of 128
    const int tid = threadIdx.x;
    const int wave = tid >> 6;
    const int lane = tid & 63;
    const int c32 = lane & 31;
    const int l5 = lane >> 5;

    const int wrow0 = rt * BLK_ROWS + wave * 32;
    const int col0 = ch * CHUNK_COLS;

    // A fragments (frag-panel, coalesced 16B/lane): 4 ks x i32x4
    i32x4 a[4];
    {
        const unsigned char* apan = F4 + (size_t)(wrow0 >> 6) * 8192
                                    + (size_t)(((wrow0 >> 5) & 1) * 64 + lane) * 16;
#pragma unroll
        for (int ks = 0; ks < 4; ++ks)
            a[ks] = *reinterpret_cast<const i32x4*>(apan + ks * 2048);
    }

    // stage 128-col tile t (two panels = contiguous 16KB); 4 chunks/thread
    auto stage = [&](int buf, int t) {
        const unsigned char* src = F4 + (size_t)(ch * 4 + t) * 16384;
#pragma unroll
        for (int i2 = 0; i2 < 4; ++i2) {
            __builtin_amdgcn_global_load_lds((gas_uint*)(src + (i2 * 256 + tid) * 16),
                                             (las_uint*)(&Bsm[buf][(i2 * 256 + wave * 64) * 16]),
                                             16, 0, 0);
        }
    };

    float sums[16];
#pragma unroll
    for (int g = 0; g < 16; ++g) sums[g] = 0.0f;

    stage(0, 0);
    asm volatile("s_waitcnt vmcnt(0)");
    __syncthreads();

    for (int t = 0; t < NTILE; ++t) {
        const int buf = t & 1;
        if (t + 1 < NTILE) stage(buf ^ 1, t + 1);

        // two 64-col halves per tile; register shape identical to v11
#pragma unroll
        for (int h = 0; h < 2; ++h) {
            f32x16 acc0 = {};
            f32x16 acc1 = {};
#pragma unroll
            for (int ks = 0; ks < 4; ++ks) {
                const unsigned char* base = &Bsm[buf][h * 8192 + ks * 2048 + lane * 16];
                const i32x4 b0 = *reinterpret_cast<const i32x4*>(base);
                const i32x4 b1 = *reinterpret_cast<const i32x4*>(base + 1024);
                acc0 = __builtin_amdgcn_mfma_scale_f32_32x32x64_f8f6f4(
                    pad8(a[ks]), pad8(b0), acc0, 4, 4, 0, 0x7B7B7B7B, 0, 0x7B7B7B7B);
                acc1 = __builtin_amdgcn_mfma_scale_f32_32x32x64_f8f6f4(
                    pad8(a[ks]), pad8(b1), acc1, 4, 4, 0, 0x7B7B7B7B, 0, 0x7B7B7B7B);
            }

            const int cb = col0 + t * 128 + h * 64;
            const bool d0 = (wrow0 == cb);
            const bool d1 = (wrow0 == cb + 32);
            if (d0 | d1) {
#pragma unroll
                for (int g = 0; g < 16; ++g) {
                    const int rowid = (g & 3) + 8 * (g >> 2) + 4 * l5;
                    float e0 = exp2f(acc0[g]);
                    float e1 = exp2f(acc1[g]);
                    if (d0 && rowid == c32) e0 = 0.0f;
                    if (d1 && rowid == c32) e1 = 0.0f;
                    sums[g] += e0 + e1;
                }
            } else {
#pragma unroll
                for (int g = 0; g < 16; ++g)
                    sums[g] += exp2f(acc0[g]) + exp2f(acc1[g]);
            }
        }

        asm volatile("s_waitcnt vmcnt(0)");
        __syncthreads();
    }

    // reduce each row's partial across the 32 lanes holding its columns
#pragma unroll
    for (int g = 0; g < 16; ++g) {
        float s = sums[g];
        s += __shfl_xor(s, 1, 64);
        s += __shfl_xor(s, 2, 64);
        s += __shfl_xor(s, 4, 64);
        s += __shfl_xor(s, 8, 64);
        s += __shfl_xor(s, 16, 64);
        if (c32 == 0) {
            const int row = wrow0 + (g & 3) + 8 * (g >> 2) + 4 * l5;
            Spart[(size_t)ch * NTOT + row] = s;
        }
    }
}

// K3a: 32 blocks x 256 thr, one row each: S = sum chunks, local = log(S)-pos.
__global__ __launch_bounds__(256) void k_reduce(const float* __restrict__ Spart,
                                                const float* __restrict__ pos_sim,
                                                float* __restrict__ Bpart) {
    __shared__ float red[4];
    const int r = blockIdx.x * 256 + threadIdx.x;
    float s = 0.0f;
#pragma unroll
    for (int c = 0; c < NCHUNK; ++c) s += Spart[(size_t)c * NTOT + r];
    float local = logf(s) - pos_sim[r];
    local = wave_reduce_add(local);
    if ((threadIdx.x & 63) == 0) red[threadIdx.x >> 6] = local;
    __syncthreads();
    if (threadIdx.x == 0) Bpart[blockIdx.x] = red[0] + red[1] + red[2] + red[3];
}

// K3b: single wave folds 32 block partials.
__global__ void k_fin(const float* __restrict__ Bpart, float* __restrict__ out) {
    float v = (threadIdx.x < 32) ? Bpart[threadIdx.x] : 0.0f;
    v = wave_reduce_add(v);
    if (threadIdx.x == 0) out[0] = v / ((float)NTOT * (float)NTOT);
}

extern "C" void kernel_launch(void* const* d_in, const int* in_sizes, int n_in,
                              void* d_out, int out_size, void* d_ws, size_t ws_size,
                              hipStream_t stream) {
    (void)in_sizes; (void)n_in; (void)out_size; (void)ws_size;
    const float* zi = (const float*)d_in[0];
    const float* zj = (const float*)d_in[1];
    float* out = (float*)d_out;

    char* ws = (char*)d_ws;
    unsigned char* F4 = (unsigned char*)ws;                     // 1 MiB fp4 feats, frag-panel order
    float* pos_sim = (float*)(ws + 1048576);                    // 32 KiB
    float* Spart = (float*)(ws + 1048576 + 65536);              // 512 KiB (16 chunks)
    float* Bpart = (float*)(ws + 1048576 + 65536 + 524288);     // 128 B

    k_norm<<<B_ROWS / 4, 256, 0, stream>>>(zi, zj, F4, pos_sim);
    k_simsum<<<1024, 256, 0, stream>>>(F4, Spart);
    k_reduce<<<NTOT / 256, 256, 0, stream>>>(Spart, pos_sim, Bpart);
    k_fin<<<1, 64, 0, stream>>>(Bpart, out);
}